// Round 5
// baseline (158.986 us; speedup 1.0000x reference)
//
#include <hip/hip_runtime.h>
#include <hip/hip_cooperative_groups.h>

namespace cg = cooperative_groups;

#define NB 32
#define NC 256
#define HW 4096   // 64*64
#define RDIM 16   // C/R = 256/16
#define KTOP 128

typedef float v4f __attribute__((ext_vector_type(4)));

// ---------------------------------------------------------------------------
// Shared device helper: SE-MLP + sigmoid + top-k(128) into LDS (sidx, saw).
// Must be called by all 256 threads of the block.
// ---------------------------------------------------------------------------
__device__ __forceinline__ void se_topk_lds(
    int b, int t, int wid, int lane,
    const float* __restrict__ y,
    const float* __restrict__ w1, const float* __restrict__ b1,
    const float* __restrict__ w2, const float* __restrict__ b2,
    float* ych, float* hsh, float* attn, unsigned long long* masks,
    int* sidx, float* saw) {
    ych[t] = y[b * NC + t];
    __syncthreads();

    // h[r] = relu(sum_c y[c]*w1[r,c] + b1[r]); 16 groups of 16 lanes.
    const int r = t >> 4;
    const int j = t & 15;
    float partial = 0.f;
#pragma unroll
    for (int k = 0; k < 16; ++k) {
        const int c = j * 16 + k;
        partial += ych[c] * w1[r * NC + c];
    }
#pragma unroll
    for (int m = 8; m > 0; m >>= 1) partial += __shfl_xor(partial, m, 16);
    if (j == 0) hsh[r] = fmaxf(partial + b1[r], 0.f);
    __syncthreads();

    // attn[c] = sigmoid(sum_r h[r]*w2[c,r] + b2[c]).
    float z = b2[t];
#pragma unroll
    for (int rr = 0; rr < RDIM; ++rr) z += hsh[rr] * w2[t * RDIM + rr];
    const float v = 1.0f / (1.0f + __expf(-z));
    attn[t] = v;
    __syncthreads();

    // rank (strict order, tie -> lower index wins == jax.lax.top_k).
    int rank = 0;
#pragma unroll 4
    for (int c = 0; c < NC; ++c) {
        const float o = attn[c];
        rank += (o > v) || (o == v && c < t);
    }
    const bool s = (rank < KTOP);

    // ballot-based compaction into LDS (ascending channel index).
    const unsigned long long m = __ballot(s);
    if (lane == 0) masks[wid] = m;
    __syncthreads();
    if (s) {
        int pos = __popcll(m & ((lane == 63) ? 0x7FFFFFFFFFFFFFFFull
                                             : ((1ull << lane) - 1ull)));
        for (int w = 0; w < 4; ++w) pos += (w < wid) ? __popcll(masks[w]) : 0;
        sidx[pos] = t;
        saw[pos]  = v;
    }
    __syncthreads();
}

// ---------------------------------------------------------------------------
// Cooperative fused kernel. 512 blocks x 256 threads (only 2 blocks/CU
// co-residency needed). Phase 1: block pools 16 planes of its batch.
// grid.sync(). Phase 2: SE-MLP+topk in LDS, gather 8 planes of same batch.
// ---------------------------------------------------------------------------
__global__ __launch_bounds__(256, 2) void ca_fused_kernel(
    const float* __restrict__ x, float* __restrict__ y,
    const float* __restrict__ w1, const float* __restrict__ b1,
    const float* __restrict__ w2, const float* __restrict__ b2,
    float* __restrict__ out) {
    const int blk  = blockIdx.x;                        // 0..511
    const int b    = blk >> 4;                          // 16 blocks / batch
    const int t    = threadIdx.x;
    const int wid  = t >> 6, lane = t & 63;

    // ---- Phase 1: pool 16 planes (4 per wave), all within batch b ----
#pragma unroll 1
    for (int rep = 0; rep < 4; ++rep) {
        const int plane = blk * 16 + wid * 4 + rep;     // = b*NC + c
        const v4f* __restrict__ xin = (const v4f*)(x + (size_t)plane * HW);
        float s = 0.f;
#pragma unroll
        for (int i = 0; i < 16; ++i) {                  // 1024 v4 / 64 lanes
            v4f v = xin[lane + i * 64];
            s += (v.x + v.y) + (v.z + v.w);
        }
#pragma unroll
        for (int off = 32; off > 0; off >>= 1) s += __shfl_down(s, off);
        if (lane == 0) y[plane] = s * (1.0f / HW);
    }
    __threadfence();
    cg::this_grid().sync();

    // ---- Phase 2: SE-MLP + top-k, then gather 8 planes (2 per wave) ----
    __shared__ float ych[NC];
    __shared__ float hsh[RDIM];
    __shared__ float attn[NC];
    __shared__ unsigned long long masks[4];
    __shared__ int   sidx[KTOP];
    __shared__ float saw[KTOP];
    se_topk_lds(b, t, wid, lane, y, w1, b1, w2, b2,
                ych, hsh, attn, masks, sidx, saw);

#pragma unroll 1
    for (int rep = 0; rep < 2; ++rep) {
        const int k = (blk & 15) * 8 + wid * 2 + rep;   // 0..KTOP-1
        const int c = sidx[k];
        const float w = saw[k];
        const v4f* __restrict__ xin = (const v4f*)(x + ((size_t)b * NC + c) * HW);
        v4f* __restrict__ o = (v4f*)(out + ((size_t)b * KTOP + k) * HW);
#pragma unroll
        for (int i = 0; i < 16; ++i) {
            v4f vv = xin[lane + i * 64];
            v4f rr = vv * w;
            __builtin_nontemporal_store(rr, &o[lane + i * 64]);
        }
    }
}

// ---------------------------------------------------------------------------
// Fallback path (proven R3 kernels) in case cooperative launch is rejected.
// ---------------------------------------------------------------------------
__global__ __launch_bounds__(256) void pool_kernel(const float* __restrict__ x,
                                                   float* __restrict__ y) {
    const int wid  = threadIdx.x >> 6;
    const int lane = threadIdx.x & 63;
    const int plane = blockIdx.x * 4 + wid;
    const v4f* __restrict__ xin = (const v4f*)(x + (size_t)plane * HW);
    float s = 0.f;
#pragma unroll
    for (int i = 0; i < 16; ++i) {
        v4f v = xin[lane + i * 64];
        s += (v.x + v.y) + (v.z + v.w);
    }
#pragma unroll
    for (int off = 32; off > 0; off >>= 1) s += __shfl_down(s, off);
    if (lane == 0) y[plane] = s * (1.0f / HW);
}

__global__ __launch_bounds__(256) void se_topk_gather_kernel(
    const float* __restrict__ x, const float* __restrict__ y,
    const float* __restrict__ w1, const float* __restrict__ b1,
    const float* __restrict__ w2, const float* __restrict__ b2,
    float* __restrict__ out) {
    const int blk = blockIdx.x;                         // 0..1023
    const int b   = blk >> 5;
    const int t   = threadIdx.x;
    const int wid = t >> 6, lane = t & 63;

    __shared__ float ych[NC];
    __shared__ float hsh[RDIM];
    __shared__ float attn[NC];
    __shared__ unsigned long long masks[4];
    __shared__ int   sidx[KTOP];
    __shared__ float saw[KTOP];
    se_topk_lds(b, t, wid, lane, y, w1, b1, w2, b2,
                ych, hsh, attn, masks, sidx, saw);

    const int k = (blk & 31) * 4 + wid;
    const int c = sidx[k];
    const float w = saw[k];
    const v4f* __restrict__ xin = (const v4f*)(x + ((size_t)b * NC + c) * HW);
    v4f* __restrict__ o = (v4f*)(out + ((size_t)b * KTOP + k) * HW);
#pragma unroll
    for (int i = 0; i < 16; ++i) {
        v4f vv = xin[lane + i * 64];
        v4f rr = vv * w;
        __builtin_nontemporal_store(rr, &o[lane + i * 64]);
    }
}

// ---------------------------------------------------------------------------
extern "C" void kernel_launch(void* const* d_in, const int* in_sizes, int n_in,
                              void* d_out, int out_size, void* d_ws, size_t ws_size,
                              hipStream_t stream) {
    const float* x  = (const float*)d_in[0];
    const float* w1 = (const float*)d_in[1];
    const float* b1 = (const float*)d_in[2];
    const float* w2 = (const float*)d_in[3];
    const float* b2 = (const float*)d_in[4];
    float* out = (float*)d_out;
    float* y   = (float*)d_ws;                          // y[NB*NC]

    void* args[] = { (void*)&x, (void*)&y, (void*)&w1, (void*)&b1,
                     (void*)&w2, (void*)&b2, (void*)&out };
    hipError_t err = hipLaunchCooperativeKernel(
        (const void*)ca_fused_kernel, dim3(512), dim3(256), args, 0, stream);
    if (err != hipSuccess) {
        // Deterministic fallback: same math, two kernels.
        pool_kernel<<<NB * NC / 4, 256, 0, stream>>>(x, y);
        se_topk_gather_kernel<<<NB * KTOP / 4, 256, 0, stream>>>(
            x, y, w1, b1, w2, b2, out);
    }
}

// Round 6
// 144.722 us; speedup vs baseline: 1.0986x; 1.0986x over previous
//
#include <hip/hip_runtime.h>

#define NB 32
#define NC 256
#define HW 4096   // 64*64
#define RDIM 16   // C/R = 256/16
#define KTOP 128

typedef float v4f __attribute__((ext_vector_type(4)));

// ---------------------------------------------------------------------------
// Single fused kernel, 1024 blocks x 256 threads (4 blocks/CU -> whole grid
// co-resident at VGPR<=128, so the per-batch spin cannot deadlock).
// Block g, batch b=g>>5 (32 blocks per batch):
//   Phase 1: pool 8 planes of batch b (2 per wave), publish y via
//            device-scope atomics, release-increment cnt[b].
//   Spin:    acquire-load cnt[b] until ==32 (s_sleep between polls, bounded).
//   Phase 2: SE-MLP + sigmoid + top-k(128) in LDS (redundant per block),
//            gather+scale 4 output planes (1 per wave), NT stores.
// Batches pipeline: early batches gather (L3-hot) while late ones pool.
// ---------------------------------------------------------------------------
__global__ __launch_bounds__(256, 4) void ca_fused_spin_kernel(
    const float* __restrict__ x, float* __restrict__ y, int* __restrict__ cnt,
    const float* __restrict__ w1, const float* __restrict__ b1,
    const float* __restrict__ w2, const float* __restrict__ b2,
    float* __restrict__ out) {
    const int g   = blockIdx.x;                         // 0..1023
    const int b   = g >> 5;                             // batch
    const int t   = threadIdx.x;
    const int wid = t >> 6, lane = t & 63;

    // ---- Phase 1: pool 8 planes, 2 per wave, interleaved loads ----
    const int p0 = b * NC + (g & 31) * 8 + wid * 2;     // global plane index
    {
        const v4f* __restrict__ x0 = (const v4f*)(x + (size_t)p0 * HW);
        const v4f* __restrict__ x1 = (const v4f*)(x + (size_t)(p0 + 1) * HW);
        float s0 = 0.f, s1 = 0.f;
#pragma unroll
        for (int i = 0; i < 16; ++i) {
            v4f a = x0[lane + i * 64];
            v4f c = x1[lane + i * 64];
            s0 += (a.x + a.y) + (a.z + a.w);
            s1 += (c.x + c.y) + (c.z + c.w);
        }
#pragma unroll
        for (int off = 32; off > 0; off >>= 1) {
            s0 += __shfl_down(s0, off);
            s1 += __shfl_down(s1, off);
        }
        if (lane == 0) {
            // publish through device-scope atomics (cross-XCD coherent)
            atomicExch(&y[p0],     s0 * (1.0f / HW));
            atomicExch(&y[p0 + 1], s1 * (1.0f / HW));
        }
    }
    __syncthreads();
    if (t == 0) {
        __hip_atomic_fetch_add(&cnt[b], 1, __ATOMIC_RELEASE,
                               __HIP_MEMORY_SCOPE_AGENT);
    }

    // ---- Spin until this batch's 32 pool blocks are done ----
    if (t == 0) {
        long it = 0;
        while (__hip_atomic_load(&cnt[b], __ATOMIC_ACQUIRE,
                                 __HIP_MEMORY_SCOPE_AGENT) < 32) {
            __builtin_amdgcn_s_sleep(16);
            if (++it > 200000000L) break;               // never hard-hang
        }
    }
    __syncthreads();

    // ---- Phase 2a: SE-MLP + sigmoid + top-k in LDS ----
    __shared__ float ych[NC];
    __shared__ float hsh[RDIM];
    __shared__ float attn[NC];
    __shared__ unsigned long long masks[4];
    __shared__ int   sidx[KTOP];
    __shared__ float saw[KTOP];

    // coherent read of y (atomic no-op add returns current value)
    ych[t] = atomicAdd(&y[b * NC + t], 0.0f);
    __syncthreads();

    const int r = t >> 4;
    const int j = t & 15;
    float partial = 0.f;
#pragma unroll
    for (int k = 0; k < 16; ++k) {
        const int c = j * 16 + k;
        partial += ych[c] * w1[r * NC + c];
    }
#pragma unroll
    for (int m = 8; m > 0; m >>= 1) partial += __shfl_xor(partial, m, 16);
    if (j == 0) hsh[r] = fmaxf(partial + b1[r], 0.f);
    __syncthreads();

    float z = b2[t];
#pragma unroll
    for (int rr = 0; rr < RDIM; ++rr) z += hsh[rr] * w2[t * RDIM + rr];
    const float v = 1.0f / (1.0f + __expf(-z));
    attn[t] = v;
    __syncthreads();

    // rank (strict order, tie -> lower index wins == jax.lax.top_k).
    int rank = 0;
#pragma unroll 4
    for (int c = 0; c < NC; ++c) {
        const float o = attn[c];
        rank += (o > v) || (o == v && c < t);
    }
    const bool s = (rank < KTOP);

    // ballot-based compaction into LDS (ascending channel index).
    const unsigned long long m = __ballot(s);
    if (lane == 0) masks[wid] = m;
    __syncthreads();
    if (s) {
        int pos = __popcll(m & ((lane == 63) ? 0x7FFFFFFFFFFFFFFFull
                                             : ((1ull << lane) - 1ull)));
        for (int w = 0; w < 4; ++w) pos += (w < wid) ? __popcll(masks[w]) : 0;
        sidx[pos] = t;
        saw[pos]  = v;
    }
    __syncthreads();

    // ---- Phase 2b: gather + scale, one output plane per wave ----
    const int k = (g & 31) * 4 + wid;                   // 0..KTOP-1
    const int c = sidx[k];
    const float w = saw[k];
    const v4f* __restrict__ xin = (const v4f*)(x + ((size_t)b * NC + c) * HW);
    v4f* __restrict__ o = (v4f*)(out + ((size_t)b * KTOP + k) * HW);
#pragma unroll
    for (int i = 0; i < 16; ++i) {
        v4f vv = xin[lane + i * 64];
        v4f rr = vv * w;
        __builtin_nontemporal_store(rr, &o[lane + i * 64]);
    }
}

// ---------------------------------------------------------------------------
extern "C" void kernel_launch(void* const* d_in, const int* in_sizes, int n_in,
                              void* d_out, int out_size, void* d_ws, size_t ws_size,
                              hipStream_t stream) {
    const float* x  = (const float*)d_in[0];
    const float* w1 = (const float*)d_in[1];
    const float* b1 = (const float*)d_in[2];
    const float* w2 = (const float*)d_in[3];
    const float* b2 = (const float*)d_in[4];
    float* out = (float*)d_out;

    float* y   = (float*)d_ws;                          // y[NB*NC]
    int*   cnt = (int*)(y + NB * NC);                   // cnt[NB]

    // counters must start at 0 every call (ws is not re-poisoned between
    // replays); async memset is graph-capture-safe.
    hipMemsetAsync(cnt, 0, NB * sizeof(int), stream);

    ca_fused_spin_kernel<<<NB * NC / 8, 256, 0, stream>>>(
        x, y, cnt, w1, b1, w2, b2, out);
}

// Round 7
// 56.613 us; speedup vs baseline: 2.8083x; 2.5563x over previous
//
#include <hip/hip_runtime.h>

#define NB 32
#define NC 256
#define HW 4096   // 64*64
#define RDIM 16   // C/R = 256/16
#define KTOP 128

typedef float v4f __attribute__((ext_vector_type(4)));

// ---------------------------------------------------------------------------
// Kernel 1: global average pool. 1024 blocks x 256 threads; each wave pools
// TWO planes with interleaved loads (2x memory-level parallelism).
// ---------------------------------------------------------------------------
__global__ __launch_bounds__(256) void pool_kernel(const float* __restrict__ x,
                                                   float* __restrict__ y) {
    const int wid  = threadIdx.x >> 6;
    const int lane = threadIdx.x & 63;
    const int p0 = blockIdx.x * 8 + wid * 2;            // 0 .. NB*NC-1, step 2
    const v4f* __restrict__ x0 = (const v4f*)(x + (size_t)p0 * HW);
    const v4f* __restrict__ x1 = (const v4f*)(x + (size_t)(p0 + 1) * HW);
    float s0 = 0.f, s1 = 0.f;
#pragma unroll
    for (int i = 0; i < 16; ++i) {                      // 1024 v4 / 64 lanes
        v4f a = x0[lane + i * 64];
        v4f c = x1[lane + i * 64];
        s0 += (a.x + a.y) + (a.z + a.w);
        s1 += (c.x + c.y) + (c.z + c.w);
    }
#pragma unroll
    for (int off = 32; off > 0; off >>= 1) {
        s0 += __shfl_down(s0, off);
        s1 += __shfl_down(s1, off);
    }
    if (lane == 0) {
        y[p0]     = s0 * (1.0f / HW);
        y[p0 + 1] = s1 * (1.0f / HW);
    }
}

// ---------------------------------------------------------------------------
// Kernel 2: SE-MLP + sigmoid + top-k(128) recomputed per block in LDS, then
// gather+scale 8 planes per block (2 per wave, interleaved). 512 blocks.
// ---------------------------------------------------------------------------
__global__ __launch_bounds__(256) void se_topk_gather_kernel(
    const float* __restrict__ x, const float* __restrict__ y,
    const float* __restrict__ w1, const float* __restrict__ b1,
    const float* __restrict__ w2, const float* __restrict__ b2,
    float* __restrict__ out) {
    const int blk = blockIdx.x;                         // 0..511
    const int b   = blk >> 4;                           // 16 blocks / batch
    const int t   = threadIdx.x;
    const int wid = t >> 6, lane = t & 63;

    __shared__ float ych[NC];
    __shared__ float hsh[RDIM];
    __shared__ float attn[NC];
    __shared__ unsigned long long masks[4];
    __shared__ int   sidx[KTOP];
    __shared__ float saw[KTOP];

    ych[t] = y[b * NC + t];
    __syncthreads();

    // h[r] = relu(sum_c y[c]*w1[r,c] + b1[r]); 16 groups of 16 lanes.
    const int r = t >> 4;
    const int j = t & 15;
    float partial = 0.f;
#pragma unroll
    for (int k = 0; k < 16; ++k) {
        const int c = j * 16 + k;
        partial += ych[c] * w1[r * NC + c];
    }
#pragma unroll
    for (int m = 8; m > 0; m >>= 1) partial += __shfl_xor(partial, m, 16);
    if (j == 0) hsh[r] = fmaxf(partial + b1[r], 0.f);
    __syncthreads();

    // attn[c] = sigmoid(sum_r h[r]*w2[c,r] + b2[c]).
    float z = b2[t];
#pragma unroll
    for (int rr = 0; rr < RDIM; ++rr) z += hsh[rr] * w2[t * RDIM + rr];
    const float v = 1.0f / (1.0f + __expf(-z));
    attn[t] = v;
    __syncthreads();

    // rank (strict order, tie -> lower index wins == jax.lax.top_k).
    int rank = 0;
#pragma unroll 4
    for (int c = 0; c < NC; ++c) {
        const float o = attn[c];
        rank += (o > v) || (o == v && c < t);
    }
    const bool s = (rank < KTOP);

    // ballot-based compaction into LDS (ascending channel index).
    const unsigned long long m = __ballot(s);
    if (lane == 0) masks[wid] = m;
    __syncthreads();
    if (s) {
        int pos = __popcll(m & ((lane == 63) ? 0x7FFFFFFFFFFFFFFFull
                                             : ((1ull << lane) - 1ull)));
        for (int w = 0; w < 4; ++w) pos += (w < wid) ? __popcll(masks[w]) : 0;
        sidx[pos] = t;
        saw[pos]  = v;
    }
    __syncthreads();

    // gather + scale: TWO planes per wave, interleaved loads, NT stores.
    const int k0 = (blk & 15) * 8 + wid * 2;            // 0..KTOP-1, step 2
    const int c0 = sidx[k0],   c1 = sidx[k0 + 1];
    const float w0 = saw[k0],  w1v = saw[k0 + 1];
    const v4f* __restrict__ xa = (const v4f*)(x + ((size_t)b * NC + c0) * HW);
    const v4f* __restrict__ xb = (const v4f*)(x + ((size_t)b * NC + c1) * HW);
    v4f* __restrict__ oa = (v4f*)(out + ((size_t)b * KTOP + k0) * HW);
    v4f* __restrict__ ob = (v4f*)(out + ((size_t)b * KTOP + k0 + 1) * HW);
#pragma unroll
    for (int i = 0; i < 16; ++i) {
        v4f va = xa[lane + i * 64];
        v4f vb = xb[lane + i * 64];
        v4f ra = va * w0;
        v4f rb = vb * w1v;
        __builtin_nontemporal_store(ra, &oa[lane + i * 64]);
        __builtin_nontemporal_store(rb, &ob[lane + i * 64]);
    }
}

// ---------------------------------------------------------------------------
extern "C" void kernel_launch(void* const* d_in, const int* in_sizes, int n_in,
                              void* d_out, int out_size, void* d_ws, size_t ws_size,
                              hipStream_t stream) {
    const float* x  = (const float*)d_in[0];
    const float* w1 = (const float*)d_in[1];
    const float* b1 = (const float*)d_in[2];
    const float* w2 = (const float*)d_in[3];
    const float* b2 = (const float*)d_in[4];
    float* out = (float*)d_out;
    float* y   = (float*)d_ws;                          // y[NB*NC]

    pool_kernel<<<NB * NC / 8, 256, 0, stream>>>(x, y);
    se_topk_gather_kernel<<<NB * KTOP / 8, 256, 0, stream>>>(
        x, y, w1, b1, w2, b2, out);
}